// Round 2
// baseline (231.570 us; speedup 1.0000x reference)
//
#include <hip/hip_runtime.h>
#include <math.h>
#include <stdint.h>

#define Bn 8
#define Nn 2048
#define Cn 128
#define CP 144          // padded cols: 128 h-cols + w-col(=128) + 15 zero cols
#define NKB (Nn / 32)   // 64 k-blocks of 32
#define NPH (Nn / 128)  // 16 phases of K=128 (4 k-chunks each)

typedef _Float16 f16x8 __attribute__((ext_vector_type(8)));
typedef _Float16 f16x4 __attribute__((ext_vector_type(4)));
typedef _Float16 f16x2 __attribute__((ext_vector_type(2)));
typedef __fp16   fp16x2 __attribute__((ext_vector_type(2)));
typedef float    f32x4 __attribute__((ext_vector_type(4)));

// ---------------------------------------------------------------------------
// rows_kernel (unchanged): per 16-row chunk:
//   v[c]=Ww^T·aw2, b2=Wb·aw2, w=exp(h·v+b2),
//   hWt[b][kb][cp][ks] = f16(w_j*h[j][cp]) (cp<128), f16(w_j) at cp=128,
//   zeros cp 129..143.   grid = 8 x 128 = 1024 blocks, 256 threads.
// ---------------------------------------------------------------------------
__global__ __launch_bounds__(256) void rows_kernel(const float* __restrict__ h,
                                                   const float* __restrict__ Ww,
                                                   const float* __restrict__ Wb,
                                                   const float* __restrict__ aw,
                                                   _Float16* __restrict__ hWt) {
    __shared__ float tile[16][132];
    __shared__ float vlo[128];
    __shared__ float vhi[128];
    __shared__ float wsh[16];
    __shared__ float b2sh;

    int bid = blockIdx.x;
    int b   = bid & 7;
    int n0  = (bid >> 3) << 4;
    int tid = threadIdx.x;

    {   // v halves
        int c = tid & 127, half = tid >> 7;
        float acc = 0.f;
#pragma unroll
        for (int dd = 0; dd < 64; ++dd) {
            int d = half * 64 + dd;
            acc += Ww[d * Cn + c] * aw[Cn + d];
        }
        if (half) vhi[c] = acc; else vlo[c] = acc;
    }
    if (tid < 64) {
        float b2p = Wb[tid] * aw[Cn + tid] + Wb[tid + 64] * aw[Cn + tid + 64];
        b2p += __shfl_xor(b2p, 32, 64);
        b2p += __shfl_xor(b2p, 16, 64);
        b2p += __shfl_xor(b2p, 8, 64);
        b2p += __shfl_xor(b2p, 4, 64);
        b2p += __shfl_xor(b2p, 2, 64);
        b2p += __shfl_xor(b2p, 1, 64);
        if (tid == 0) b2sh = b2p;
    }
    {   // stage 16x128 h tile
#pragma unroll
        for (int i = 0; i < 2; ++i) {
            int idx = tid + 256 * i;
            int r = idx >> 5, f4 = idx & 31;
            *(float4*)&tile[r][f4 * 4] =
                ((const float4*)(h + (size_t)(b * Nn + n0 + r) * Cn))[f4];
        }
    }
    __syncthreads();

    {   // w = exp(h·v + b2)
        int r = tid >> 4, g = tid & 15;
        float acc = 0.f;
#pragma unroll
        for (int ii = 0; ii < 8; ++ii) {
            int i = g * 8 + ii;
            acc += tile[r][i] * (vlo[i] + vhi[i]);
        }
        acc += __shfl_xor(acc, 1, 64);
        acc += __shfl_xor(acc, 2, 64);
        acc += __shfl_xor(acc, 4, 64);
        acc += __shfl_xor(acc, 8, 64);
        if (g == 0) wsh[r] = expf(acc + b2sh);
    }
    __syncthreads();

    {   // hWt stores: 144 cp x 8 pairs = 1152 f16x2
        int kb = n0 >> 5, khalf = (n0 >> 4) & 1;
        _Float16* hWb = hWt + ((size_t)(b * NKB + kb) * CP) * 32 + khalf * 16;
#pragma unroll
        for (int i = 0; i < 5; ++i) {
            int idx = tid + 256 * i;
            if (idx < 1152) {
                int cp = idx >> 3, p = idx & 7;
                int r0 = p * 2;
                f16x2 v2;
                if (cp < 128) {
                    v2[0] = (_Float16)(wsh[r0] * tile[r0][cp]);
                    v2[1] = (_Float16)(wsh[r0 + 1] * tile[r0 + 1][cp]);
                } else if (cp == 128) {
                    v2[0] = (_Float16)wsh[r0];
                    v2[1] = (_Float16)wsh[r0 + 1];
                } else {
                    v2[0] = (_Float16)0.f;
                    v2[1] = (_Float16)0.f;
                }
                *(f16x2*)(hWb + (size_t)cp * 32 + p * 2) = v2;
            }
        }
    }
}

// ---------------------------------------------------------------------------
// attn_kernel v3: f16 GEMM out' = A @ hW, row-normalize epilogue.
// M=32/block, grid 8x64=512 (2 blocks/CU), 512 thr = 8 waves.
// Phase = K=128 (4 k-chunks of 32): 16 phases, 1 barrier each (was 32).
// Wave w owns c-tile w (cols w*16..+15) for both m-tiles: every wave does
// exactly 8 MFMA + 4 B-loads per phase — no conditionals in the hot loop.
// Denominator den_i = sum_j A_ij*w_j computed as scalar VALU work folded
// into the staging path: each staging thread loads its 8 f16 w values
// (cp=128 row, L2-hot) and accumulates dacc += f16(A)*w in f32 (uses the
// SAME f16-rounded A as the numerator MFMA so rounding cancels in the
// ratio).  Epilogue: 4-step shfl_xor over the 16 lanes sharing a row.
// A staged f32->f16 in LDS (one ds_write_b128/thread/phase), double-
// buffered; A-globals 2-phase prefetch, B-frags + w-frags 1-phase register
// prefetch.
// ---------------------------------------------------------------------------
__global__ __launch_bounds__(512, 4) void attn_kernel(const float* __restrict__ A,
                                                      const _Float16* __restrict__ hWt,
                                                      float* __restrict__ out) {
    __shared__ __align__(16) _Float16 Af[2][4][32][40];  // [buf][chunk][row][kpad40]
    __shared__ float den[32];

    int bid = blockIdx.x;
    int b   = bid & 7;                      // XCD-aligned batch
    int i0  = (bid >> 3) << 5;              // 64 row-blocks of 32
    int tid = threadIdx.x;
    int wv  = tid >> 6, l = tid & 63;
    int m   = l & 15, q = l >> 4;

    const float*    Ab  = A   + (size_t)(b * Nn + i0) * Nn;
    const _Float16* hWb = hWt + (size_t)b * NKB * CP * 32;

    // staging map: 32 rows x 128 k f32 per phase; 16 thr/row, 32 B (8 floats) each
    int sr = tid >> 4, sf4 = tid & 15;
    const float* sg = Ab + (size_t)sr * Nn + sf4 * 8;
    int sch = sf4 >> 2, skl = (sf4 & 3) * 8;
    // w-frag base: chunk kb = 4t + sch, cp = 128, ks = skl
    const _Float16* wg = hWb + ((size_t)sch * CP + 128) * 32 + skl;

    f32x4 accc[2];                          // own c-tile, m-tiles 0/1
    accc[0] = (f32x4){0.f, 0.f, 0.f, 0.f};
    accc[1] = (f32x4){0.f, 0.f, 0.f, 0.f};
    float dacc = 0.f;                       // den partial: row sr, own 8 k's/phase

    auto loadA = [&](int t, float4* a) {
        a[0] = *(const float4*)(sg + (size_t)t * 128);
        a[1] = *(const float4*)(sg + (size_t)t * 128 + 4);
    };
    auto loadW = [&](int t) {
        return *(const f16x8*)(wg + (size_t)(4 * t) * CP * 32);
    };
    auto storeA = [&](int t, const float4* a, f16x8 wf) {
        union { fp16x2 h2[4]; f16x8 v8; } u;
        u.h2[0] = __builtin_amdgcn_cvt_pkrtz(a[0].x, a[0].y);
        u.h2[1] = __builtin_amdgcn_cvt_pkrtz(a[0].z, a[0].w);
        u.h2[2] = __builtin_amdgcn_cvt_pkrtz(a[1].x, a[1].y);
        u.h2[3] = __builtin_amdgcn_cvt_pkrtz(a[1].z, a[1].w);
        *(f16x8*)&Af[t & 1][sch][sr][skl] = u.v8;
        float s = 0.f;
#pragma unroll
        for (int i = 0; i < 8; ++i)
            s += (float)u.v8[i] * (float)wf[i];
        dacc += s;
    };
    auto loadB = [&](int t, f16x8* bf) {    // bf[0..3] = own c-tile, 4 chunks
#pragma unroll
        for (int j = 0; j < 4; ++j)
            bf[j] = *(const f16x8*)(hWb + ((size_t)(4 * t + j) * CP + wv * 16 + m) * 32 + q * 8);
    };
    auto compute = [&](int buf, const f16x8* bf) {
#pragma unroll
        for (int j = 0; j < 4; ++j) {
            f16x8 af0 = *(const f16x8*)&Af[buf][j][m][q * 8];        // m-tile 0
            f16x8 af1 = *(const f16x8*)&Af[buf][j][16 + m][q * 8];   // m-tile 1
            accc[0] = __builtin_amdgcn_mfma_f32_16x16x32_f16(af0, bf[j], accc[0], 0, 0, 0);
            accc[1] = __builtin_amdgcn_mfma_f32_16x16x32_f16(af1, bf[j], accc[1], 0, 0, 0);
        }
    };

    // preamble: A(0),A(1) in regs; B(0),w(0) in regs; buf0 <- A(0)
    float4 a0[2], a1[2];
    f16x8 bfA[4], bfB[4], wfA, wfB;
    loadA(0, a0);
    loadA(1, a1);
    loadB(0, bfA);
    wfA = loadW(0);
    storeA(0, a0, wfA);
    __syncthreads();

    for (int t2 = 0; t2 < NPH / 2; ++t2) {
        int te = 2 * t2, to = te + 1;
        // phase te (even, buf0, frags bfA)
        loadB(to, bfB);
        wfB = loadW(to);
        if (t2 < NPH / 2 - 1) loadA(te + 2, a0);
        compute(0, bfA);
        storeA(to, a1, wfB);                // buf1 <- A(te+1), den += A(te+1)·w
        __syncthreads();
        // phase to (odd, buf1, frags bfB)
        if (t2 < NPH / 2 - 1) {
            loadB(to + 1, bfA);
            wfA = loadW(to + 1);
            loadA(to + 2, a1);
        }
        compute(1, bfB);
        if (t2 < NPH / 2 - 1) storeA(to + 1, a0, wfA);   // buf0 <- A(te+2)
        __syncthreads();
    }

    // denominator: reduce dacc over the 16 lanes sharing row sr
    dacc += __shfl_xor(dacc, 1, 64);
    dacc += __shfl_xor(dacc, 2, 64);
    dacc += __shfl_xor(dacc, 4, 64);
    dacc += __shfl_xor(dacc, 8, 64);
    if (sf4 == 0) den[sr] = dacc;
    __syncthreads();

#pragma unroll
    for (int mt = 0; mt < 2; ++mt) {
#pragma unroll
        for (int r = 0; r < 4; ++r) {
            int row = mt * 16 + q * 4 + r;
            float invd = 1.f / den[row];
            out[(size_t)(b * Nn + i0 + row) * Cn + wv * 16 + m] = accc[mt][r] * invd;
        }
    }
}

// ---------------------------------------------------------------------------
extern "C" void kernel_launch(void* const* d_in, const int* in_sizes, int n_in,
                              void* d_out, int out_size, void* d_ws, size_t ws_size,
                              hipStream_t stream) {
    const float* h  = (const float*)d_in[0];
    const float* A  = (const float*)d_in[1];
    const float* Ww = (const float*)d_in[2];
    const float* Wb = (const float*)d_in[3];
    const float* aw = (const float*)d_in[4];
    // d_in[5] = a_b : cancels in the row normalization, unused
    float* out = (float*)d_out;

    _Float16* hWt = (_Float16*)d_ws;        // 8*64*144*32 f16 = 4.72 MB

    rows_kernel<<<Bn * (Nn / 16), 256, 0, stream>>>(h, Ww, Wb, aw, hWt);
    attn_kernel<<<Bn * (Nn / 32), 512, 0, stream>>>(A, hWt, out);
}

// Round 4
// 225.589 us; speedup vs baseline: 1.0265x; 1.0265x over previous
//
#include <hip/hip_runtime.h>
#include <math.h>
#include <stdint.h>

#define Bn 8
#define Nn 2048
#define Cn 128
#define CP 144          // padded cols: 128 h-cols + w-col(=128) + 15 zero cols
#define NKB (Nn / 32)   // 64 k-blocks of 32

typedef _Float16 f16x8 __attribute__((ext_vector_type(8)));
typedef _Float16 f16x4 __attribute__((ext_vector_type(4)));
typedef _Float16 f16x2 __attribute__((ext_vector_type(2)));
typedef __fp16   fp16x2 __attribute__((ext_vector_type(2)));
typedef float    f32x4 __attribute__((ext_vector_type(4)));

// ---------------------------------------------------------------------------
// rows_kernel (unchanged from the 222.5us baseline): per 16-row chunk:
//   v[c]=Ww^T·aw2, b2=Wb·aw2, w=exp(h·v+b2),
//   hWt[b][kb][cp][ks] = f16(w_j*h[j][cp]) (cp<128), f16(w_j) at cp=128,
//   zeros cp 129..143.   grid = 8 x 128 = 1024 blocks, 256 threads.
// ---------------------------------------------------------------------------
__global__ __launch_bounds__(256) void rows_kernel(const float* __restrict__ h,
                                                   const float* __restrict__ Ww,
                                                   const float* __restrict__ Wb,
                                                   const float* __restrict__ aw,
                                                   _Float16* __restrict__ hWt) {
    __shared__ float tile[16][132];
    __shared__ float vlo[128];
    __shared__ float vhi[128];
    __shared__ float wsh[16];
    __shared__ float b2sh;

    int bid = blockIdx.x;
    int b   = bid & 7;
    int n0  = (bid >> 3) << 4;
    int tid = threadIdx.x;

    {   // v halves
        int c = tid & 127, half = tid >> 7;
        float acc = 0.f;
#pragma unroll
        for (int dd = 0; dd < 64; ++dd) {
            int d = half * 64 + dd;
            acc += Ww[d * Cn + c] * aw[Cn + d];
        }
        if (half) vhi[c] = acc; else vlo[c] = acc;
    }
    if (tid < 64) {
        float b2p = Wb[tid] * aw[Cn + tid] + Wb[tid + 64] * aw[Cn + tid + 64];
        b2p += __shfl_xor(b2p, 32, 64);
        b2p += __shfl_xor(b2p, 16, 64);
        b2p += __shfl_xor(b2p, 8, 64);
        b2p += __shfl_xor(b2p, 4, 64);
        b2p += __shfl_xor(b2p, 2, 64);
        b2p += __shfl_xor(b2p, 1, 64);
        if (tid == 0) b2sh = b2p;
    }
    {   // stage 16x128 h tile
#pragma unroll
        for (int i = 0; i < 2; ++i) {
            int idx = tid + 256 * i;
            int r = idx >> 5, f4 = idx & 31;
            *(float4*)&tile[r][f4 * 4] =
                ((const float4*)(h + (size_t)(b * Nn + n0 + r) * Cn))[f4];
        }
    }
    __syncthreads();

    {   // w = exp(h·v + b2)
        int r = tid >> 4, g = tid & 15;
        float acc = 0.f;
#pragma unroll
        for (int ii = 0; ii < 8; ++ii) {
            int i = g * 8 + ii;
            acc += tile[r][i] * (vlo[i] + vhi[i]);
        }
        acc += __shfl_xor(acc, 1, 64);
        acc += __shfl_xor(acc, 2, 64);
        acc += __shfl_xor(acc, 4, 64);
        acc += __shfl_xor(acc, 8, 64);
        if (g == 0) wsh[r] = expf(acc + b2sh);
    }
    __syncthreads();

    {   // hWt stores: 144 cp x 8 pairs = 1152 f16x2
        int kb = n0 >> 5, khalf = (n0 >> 4) & 1;
        _Float16* hWb = hWt + ((size_t)(b * NKB + kb) * CP) * 32 + khalf * 16;
#pragma unroll
        for (int i = 0; i < 5; ++i) {
            int idx = tid + 256 * i;
            if (idx < 1152) {
                int cp = idx >> 3, p = idx & 7;
                int r0 = p * 2;
                f16x2 v2;
                if (cp < 128) {
                    v2[0] = (_Float16)(wsh[r0] * tile[r0][cp]);
                    v2[1] = (_Float16)(wsh[r0 + 1] * tile[r0 + 1][cp]);
                } else if (cp == 128) {
                    v2[0] = (_Float16)wsh[r0];
                    v2[1] = (_Float16)wsh[r0 + 1];
                } else {
                    v2[0] = (_Float16)0.f;
                    v2[1] = (_Float16)0.f;
                }
                *(f16x2*)(hWb + (size_t)cp * 32 + p * 2) = v2;
            }
        }
    }
}

// ---------------------------------------------------------------------------
// attn_kernel v5: EXACT v1 structure (K=64 phases, 32 barriers, A f32->f16
// LDS double-buffer, 1-phase B register prefetch, den on waves 0/1 with the
// proven construct, identical epilogue) with ONE change:
//   A-register prefetch depth 2 -> 4 phases.  v1 issued loadA(t+2) ~1 phase
//   (~300 cyc) before storeA consumed it; HBM latency ~900 cyc -> stall at
//   every storeA.  v5 keeps A(t+1..t+3) in 4 rotating float4 regs (p0..p3)
//   and issues loadA(t+4) at phase t: issue->consume ~3 phases >= HBM lat.
//   Loop unrolled x4 so all rotation indices are static (rule: no runtime-
//   indexed reg arrays).  +8 VGPR vs v1.
// ---------------------------------------------------------------------------
__global__ __launch_bounds__(512, 4) void attn_kernel(const float* __restrict__ A,
                                                      const _Float16* __restrict__ hWt,
                                                      float* __restrict__ out) {
    __shared__ _Float16 Af[2][2][32][40];   // [buf][chunk][row][kpad40] f16
    __shared__ float den[32];

    int bid = blockIdx.x;
    int b   = bid & 7;                      // XCD-aligned batch
    int i0  = (bid >> 3) << 5;              // 64 row-blocks of 32
    int tid = threadIdx.x;
    int wv  = tid >> 6, l = tid & 63;
    int m   = l & 15, q = l >> 4;

    const float*    Ab  = A   + (size_t)(b * Nn + i0) * Nn;
    const _Float16* hWb = hWt + (size_t)b * NKB * CP * 32;

    // staging map: thread -> (row, float4-slot); 16 thr x 64 B per row
    int sr = tid >> 4, sf4 = tid & 15;
    const float* sg = Ab + (size_t)sr * Nn + sf4 * 4;
    int sch = sf4 >> 3, skl = (sf4 & 7) * 4;

    f32x4 accc[2];                          // own c-tile, m-tiles 0/1
    f32x4 acc8;                             // den tile (waves 0,1 only)
    accc[0] = (f32x4){0.f, 0.f, 0.f, 0.f};
    accc[1] = (f32x4){0.f, 0.f, 0.f, 0.f};
    acc8    = (f32x4){0.f, 0.f, 0.f, 0.f};

    auto loadA = [&](int t) { return *(const float4*)(sg + t * 64); };
    auto storeA = [&](int t, float4 v) {
        union { fp16x2 h2[2]; f16x4 v4; } u;
        u.h2[0] = __builtin_amdgcn_cvt_pkrtz(v.x, v.y);
        u.h2[1] = __builtin_amdgcn_cvt_pkrtz(v.z, v.w);
        *(f16x4*)&Af[t & 1][sch][sr][skl] = u.v4;
    };
    auto loadB = [&](int t, f16x8* bf) {    // bf[0..1]=own c (ck 0,1); bf[2..3]=den tile
#pragma unroll
        for (int ck = 0; ck < 2; ++ck)
            bf[ck] = *(const f16x8*)(hWb + ((size_t)(2 * t + ck) * CP + wv * 16 + m) * 32 + q * 8);
        if (wv < 2) {
#pragma unroll
            for (int ck = 0; ck < 2; ++ck)
                bf[2 + ck] = *(const f16x8*)(hWb + ((size_t)(2 * t + ck) * CP + 128 + m) * 32 + q * 8);
        }
    };
    auto compute = [&](int buf, const f16x8* bf) {
#pragma unroll
        for (int ck = 0; ck < 2; ++ck) {
            f16x8 af0 = *(const f16x8*)&Af[buf][ck][m][q * 8];        // m-tile 0
            f16x8 af1 = *(const f16x8*)&Af[buf][ck][16 + m][q * 8];   // m-tile 1
            accc[0] = __builtin_amdgcn_mfma_f32_16x16x32_f16(af0, bf[ck], accc[0], 0, 0, 0);
            accc[1] = __builtin_amdgcn_mfma_f32_16x16x32_f16(af1, bf[ck], accc[1], 0, 0, 0);
            if (wv < 2)
                acc8 = __builtin_amdgcn_mfma_f32_16x16x32_f16(wv ? af1 : af0, bf[2 + ck],
                                                              acc8, 0, 0, 0);
        }
    };

    // preamble: A(0..3) in p0..p3; B(0) in bfA; buf0 <- A(0)
    float4 p0 = loadA(0);
    float4 p1 = loadA(1);
    float4 p2 = loadA(2);
    float4 p3 = loadA(3);
    f16x8 bfA[4], bfB[4];
    loadB(0, bfA);
    storeA(0, p0);                          // p0 now free
    __syncthreads();

    // invariant at phase 4g: p1=A(4g+1), p2=A(4g+2), p3=A(4g+3), p0 free
    for (int g = 0; g < 8; ++g) {
        int t0 = 4 * g;
        // phase t0 (buf0, frags bfA)
        loadB(t0 + 1, bfB);
        if (g < 7) p0 = loadA(t0 + 4);
        compute(0, bfA);
        storeA(t0 + 1, p1);                 // buf1 <- A(t0+1); p1 free
        __syncthreads();
        // phase t0+1 (buf1, frags bfB)
        loadB(t0 + 2, bfA);
        if (g < 7) p1 = loadA(t0 + 5);
        compute(1, bfB);
        storeA(t0 + 2, p2);                 // buf0 <- A(t0+2); p2 free
        __syncthreads();
        // phase t0+2 (buf0, frags bfA)
        loadB(t0 + 3, bfB);
        if (g < 7) p2 = loadA(t0 + 6);
        compute(0, bfA);
        storeA(t0 + 3, p3);                 // buf1 <- A(t0+3); p3 free
        __syncthreads();
        // phase t0+3 (buf1, frags bfB)
        if (g < 7) {
            loadB(t0 + 4, bfA);
            p3 = loadA(t0 + 7);
        }
        compute(1, bfB);
        if (g < 7) storeA(t0 + 4, p0);      // buf0 <- A(t0+4); p0 free
        __syncthreads();
        // -> invariant for phase 4(g+1): p1=A(4g+5), p2=A(4g+6), p3=A(4g+7)
    }

    // denominator: D col 0 of den tile = cp 128 = w-column  (v1 epilogue)
    if (wv < 2 && m == 0) {
#pragma unroll
        for (int r = 0; r < 4; ++r) den[wv * 16 + q * 4 + r] = acc8[r];
    }
    __syncthreads();

#pragma unroll
    for (int mt = 0; mt < 2; ++mt) {
#pragma unroll
        for (int r = 0; r < 4; ++r) {
            int row = mt * 16 + q * 4 + r;
            float invd = 1.f / den[row];
            out[(size_t)(b * Nn + i0 + row) * Cn + wv * 16 + m] = accc[mt][r] * invd;
        }
    }
}

// ---------------------------------------------------------------------------
extern "C" void kernel_launch(void* const* d_in, const int* in_sizes, int n_in,
                              void* d_out, int out_size, void* d_ws, size_t ws_size,
                              hipStream_t stream) {
    const float* h  = (const float*)d_in[0];
    const float* A  = (const float*)d_in[1];
    const float* Ww = (const float*)d_in[2];
    const float* Wb = (const float*)d_in[3];
    const float* aw = (const float*)d_in[4];
    // d_in[5] = a_b : cancels in the row normalization, unused
    float* out = (float*)d_out;

    _Float16* hWt = (_Float16*)d_ws;        // 8*64*144*32 f16 = 4.72 MB

    rows_kernel<<<Bn * (Nn / 16), 256, 0, stream>>>(h, Ww, Wb, aw, hWt);
    attn_kernel<<<Bn * (Nn / 32), 512, 0, stream>>>(A, hWt, out);
}